// Round 1
// baseline (503.583 us; speedup 1.0000x reference)
//
#include <hip/hip_runtime.h>

// MHSA fused pipeline: B=4 S=2048 D=128 H=8. fp32 in/out, bf16 MFMA internally.
// ws layout: xb(2MB) Wtq/Wtk/Wtv/Wot(256KB ea) | Qb(16MB) Kb(16MB) Vt(16MB) att(16MB) = ~67MB

typedef __attribute__((ext_vector_type(8))) short bf16x8;
typedef __attribute__((ext_vector_type(4))) float f32x4;

#define LOG2E 1.4426950408889634f

__device__ __forceinline__ unsigned short f2bf(float f) {
  unsigned u = __builtin_bit_cast(unsigned, f);
  return (unsigned short)((u + 0x7fffu + ((u >> 16) & 1u)) >> 16);
}

// ---------------- prep: convert x to bf16, transpose weights ----------------
__global__ void prep_kernel(const float* __restrict__ x, const float* __restrict__ Wq,
                            const float* __restrict__ Wk, const float* __restrict__ Wv,
                            const float* __restrict__ Wo,
                            unsigned short* __restrict__ xb, unsigned short* __restrict__ Wtq,
                            unsigned short* __restrict__ Wtk, unsigned short* __restrict__ Wtv,
                            unsigned short* __restrict__ Wot) {
  int tid = blockIdx.x * 256 + threadIdx.x;
  if (tid < 8192 * 128) xb[tid] = f2bf(x[tid]);
  if (tid < 1024 * 128) {
    int r = tid >> 7, c = tid & 127;        // Wt[n][k] = W[k][n], W is 128x1024
    Wtq[tid] = f2bf(Wq[c * 1024 + r]);
    Wtk[tid] = f2bf(Wk[c * 1024 + r]);
    Wtv[tid] = f2bf(Wv[c * 1024 + r]);
    int r2 = tid >> 10, c2 = tid & 1023;    // Wot[n][k] = Wo[k][n], Wo is 1024x128
    Wot[tid] = f2bf(Wo[c2 * 128 + r2]);
  }
}

// stage 64 rows x 128 bf16 (row stride 128) into LDS, XOR-swizzled rows of 256B
__device__ __forceinline__ void stage_64x128(unsigned short* dst, const unsigned short* gsrc, int t) {
#pragma unroll
  for (int it = 0; it < 4; ++it) {
    int c = t + it * 256;
    int row = c >> 4, col = c & 15;
    *(f32x4*)((char*)dst + row * 256 + ((col * 16) ^ ((row & 7) << 4))) =
        *(const f32x4*)(gsrc + row * 128 + col * 8);
  }
}

// 64x64 output tile from As(64x128) x Bs(64x128)^T, both swizzled
__device__ __forceinline__ void mfma_64x64(const unsigned short* As, const unsigned short* Bs,
                                           int w, int l, f32x4 acc[4]) {
  int lc = l & 15, kg = l >> 4;
#pragma unroll
  for (int kc = 0; kc < 4; ++kc) {
    int ar = w * 16 + lc;
    bf16x8 a = *(const bf16x8*)((const char*)As + ar * 256 + ((kc * 64 + kg * 16) ^ ((ar & 7) << 4)));
#pragma unroll
    for (int tt = 0; tt < 4; ++tt) {
      int br = tt * 16 + lc;
      bf16x8 b = *(const bf16x8*)((const char*)Bs + br * 256 + ((kc * 64 + kg * 16) ^ ((br & 7) << 4)));
      acc[tt] = __builtin_amdgcn_mfma_f32_16x16x32_bf16(a, b, acc[tt], 0, 0, 0);
    }
  }
}

// ---------------- Q,K projections: out[b,h,s,d] = (x @ W) * 128^-0.25 ----------------
__global__ __launch_bounds__(256) void proj_qk_kernel(const unsigned short* __restrict__ xb,
    const unsigned short* __restrict__ Wtq, const unsigned short* __restrict__ Wtk,
    unsigned short* __restrict__ Qb, unsigned short* __restrict__ Kb) {
  __shared__ unsigned short As[64 * 128], Bs[64 * 128];
  const unsigned short* Wt = blockIdx.z ? Wtk : Wtq;
  unsigned short* Out = blockIdx.z ? Kb : Qb;
  int m0 = blockIdx.x * 64, n0 = blockIdx.y * 64;
  int t = threadIdx.x, w = t >> 6, l = t & 63, lc = l & 15, kg = l >> 4;
  stage_64x128(As, xb + m0 * 128, t);
  stage_64x128(Bs, Wt + n0 * 128, t);
  __syncthreads();
  f32x4 acc[4];
#pragma unroll
  for (int i = 0; i < 4; ++i) acc[i] = (f32x4){0.f, 0.f, 0.f, 0.f};
  mfma_64x64(As, Bs, w, l, acc);
  const float scale = 0.29730177875068026f;  // 128^-0.25
#pragma unroll
  for (int tt = 0; tt < 4; ++tt)
#pragma unroll
    for (int e = 0; e < 4; ++e) {
      int m = m0 + w * 16 + kg * 4 + e;
      int n = n0 + tt * 16 + lc;
      int b = m >> 11, s = m & 2047, h = n >> 7, d = n & 127;
      Out[((b * 8 + h) * 2048 + s) * 128 + d] = f2bf(acc[tt][e] * scale);
    }
}

// ---------------- V projection, transposed: Vt[b,h,d,s] = (x @ Wv)^T ----------------
__global__ __launch_bounds__(256) void proj_v_kernel(const unsigned short* __restrict__ xb,
    const unsigned short* __restrict__ Wtv, unsigned short* __restrict__ Vt) {
  __shared__ unsigned short As[64 * 128], Bs[64 * 128];
  int n0 = blockIdx.x * 64;  // rows of Wv^T (n = h*128+d)
  int t0 = blockIdx.y * 64;  // tokens
  int t = threadIdx.x, w = t >> 6, l = t & 63, lc = l & 15, kg = l >> 4;
  stage_64x128(As, Wtv + n0 * 128, t);
  stage_64x128(Bs, xb + t0 * 128, t);
  __syncthreads();
  f32x4 acc[4];
#pragma unroll
  for (int i = 0; i < 4; ++i) acc[i] = (f32x4){0.f, 0.f, 0.f, 0.f};
  mfma_64x64(As, Bs, w, l, acc);
#pragma unroll
  for (int tt = 0; tt < 4; ++tt)
#pragma unroll
    for (int e = 0; e < 4; ++e) {
      int n = n0 + w * 16 + kg * 4 + e;
      int m = t0 + tt * 16 + lc;
      int b = m >> 11, s = m & 2047, h = n >> 7, d = n & 127;
      Vt[((b * 8 + h) * 128 + d) * 2048 + s] = f2bf(acc[tt][e]);
    }
}

// ---------------- flash attention: per (b,h), Q-tile 128, KV-tile 64 ----------------
__global__ __launch_bounds__(256) void attn_kernel(const unsigned short* __restrict__ Qb,
    const unsigned short* __restrict__ Kb, const unsigned short* __restrict__ Vt,
    unsigned short* __restrict__ att) {
  __shared__ unsigned short lds[24576];  // 48 KB
  int bh = blockIdx.y;
  int q0 = blockIdx.x * 128;
  const unsigned short* Qp = Qb + bh * 2048 * 128;
  const unsigned short* Kp = Kb + bh * 2048 * 128;
  const unsigned short* Vp = Vt + bh * 128 * 2048;
  int t = threadIdx.x, w = t >> 6, l = t & 63, lc = l & 15, kg = l >> 4;

  // stage Q tile (128x128) into lds[0..32KB), then pull into registers
#pragma unroll
  for (int it = 0; it < 8; ++it) {
    int c = t + it * 256;
    int row = c >> 4, col = c & 15;
    *(f32x4*)((char*)lds + row * 256 + ((col * 16) ^ ((row & 7) << 4))) =
        *(const f32x4*)(Qp + (q0 + row) * 128 + col * 8);
  }
  __syncthreads();
  bf16x8 qf[2][4];
#pragma unroll
  for (int mr = 0; mr < 2; ++mr)
#pragma unroll
    for (int kc = 0; kc < 4; ++kc) {
      int row = w * 32 + mr * 16 + lc;
      qf[mr][kc] = *(const bf16x8*)((const char*)lds + row * 256 + ((kc * 64 + kg * 16) ^ ((row & 7) << 4)));
    }
  __syncthreads();

  unsigned short* Ks = lds;           // bytes [0,16384): 64 rows x 256B
  unsigned short* Vs = lds + 8192;    // bytes [16384,32768): 128 rows x 128B (V^T)
  unsigned short* Ps = lds + 16384;   // bytes [32768,49152): 128 rows x 128B (P, per-wave)

  f32x4 acc_o[2][8];
  float m_run[2][4], l_run[2][4];
#pragma unroll
  for (int mr = 0; mr < 2; ++mr) {
#pragma unroll
    for (int tt = 0; tt < 8; ++tt) acc_o[mr][tt] = (f32x4){0.f, 0.f, 0.f, 0.f};
#pragma unroll
    for (int e = 0; e < 4; ++e) { m_run[mr][e] = -1e30f; l_run[mr][e] = 0.f; }
  }

  for (int kv0 = 0; kv0 < 2048; kv0 += 64) {
    // stage K (64x128) and V^T (128x64)
#pragma unroll
    for (int it = 0; it < 4; ++it) {
      int c = t + it * 256;
      int row = c >> 4, col = c & 15;
      *(f32x4*)((char*)Ks + row * 256 + ((col * 16) ^ ((row & 7) << 4))) =
          *(const f32x4*)(Kp + (kv0 + row) * 128 + col * 8);
      int vr = c >> 3, vcol = c & 7;
      *(f32x4*)((char*)Vs + vr * 128 + ((vcol * 16) ^ ((vr & 7) << 4))) =
          *(const f32x4*)(Vp + vr * 2048 + kv0 + vcol * 8);
    }
    __syncthreads();

    // QK^T: 32 q rows x 64 kv cols per wave
    f32x4 sc[2][4];
#pragma unroll
    for (int mr = 0; mr < 2; ++mr)
#pragma unroll
      for (int tt = 0; tt < 4; ++tt) sc[mr][tt] = (f32x4){0.f, 0.f, 0.f, 0.f};
#pragma unroll
    for (int kc = 0; kc < 4; ++kc) {
      bf16x8 bk[4];
#pragma unroll
      for (int tt = 0; tt < 4; ++tt) {
        int row = tt * 16 + lc;
        bk[tt] = *(const bf16x8*)((const char*)Ks + row * 256 + ((kc * 64 + kg * 16) ^ ((row & 7) << 4)));
      }
#pragma unroll
      for (int mr = 0; mr < 2; ++mr)
#pragma unroll
        for (int tt = 0; tt < 4; ++tt)
          sc[mr][tt] = __builtin_amdgcn_mfma_f32_16x16x32_bf16(qf[mr][kc], bk[tt], sc[mr][tt], 0, 0, 0);
    }

    // online softmax: row i = 4*kg+e lives in lanes [kg*16, kg*16+16)
#pragma unroll
    for (int mr = 0; mr < 2; ++mr)
#pragma unroll
      for (int e = 0; e < 4; ++e) {
        float mx = fmaxf(fmaxf(sc[mr][0][e], sc[mr][1][e]), fmaxf(sc[mr][2][e], sc[mr][3][e]));
        mx = fmaxf(mx, __shfl_xor(mx, 1));
        mx = fmaxf(mx, __shfl_xor(mx, 2));
        mx = fmaxf(mx, __shfl_xor(mx, 4));
        mx = fmaxf(mx, __shfl_xor(mx, 8));
        float mnew = fmaxf(m_run[mr][e], mx);
        float resc = exp2f((m_run[mr][e] - mnew) * LOG2E);
        float rs = 0.f;
#pragma unroll
        for (int tt = 0; tt < 4; ++tt) {
          float p = exp2f((sc[mr][tt][e] - mnew) * LOG2E);
          sc[mr][tt][e] = p;
          rs += p;
        }
        rs += __shfl_xor(rs, 1);
        rs += __shfl_xor(rs, 2);
        rs += __shfl_xor(rs, 4);
        rs += __shfl_xor(rs, 8);
        m_run[mr][e] = mnew;
        l_run[mr][e] = l_run[mr][e] * resc + rs;
#pragma unroll
        for (int tt = 0; tt < 8; ++tt) acc_o[mr][tt][e] *= resc;
      }

    // P -> LDS (bf16), wave-private region: no cross-wave barrier needed
#pragma unroll
    for (int mr = 0; mr < 2; ++mr)
#pragma unroll
      for (int tt = 0; tt < 4; ++tt)
#pragma unroll
        for (int e = 0; e < 4; ++e) {
          int row = w * 32 + mr * 16 + kg * 4 + e;
          int colb = (tt * 16 + lc) * 2;
          *(unsigned short*)((char*)Ps + row * 128 + (colb ^ ((row & 7) << 4))) = f2bf(sc[mr][tt][e]);
        }

    // PV: acc_o += P @ V  (V^T rows from Vs)
#pragma unroll
    for (int kc = 0; kc < 2; ++kc) {
      bf16x8 pa[2];
#pragma unroll
      for (int mr = 0; mr < 2; ++mr) {
        int row = w * 32 + mr * 16 + lc;
        pa[mr] = *(const bf16x8*)((const char*)Ps + row * 128 + ((kc * 64 + kg * 16) ^ ((row & 7) << 4)));
      }
#pragma unroll
      for (int tt = 0; tt < 8; ++tt) {
        int row = tt * 16 + lc;
        bf16x8 bv = *(const bf16x8*)((const char*)Vs + row * 128 + ((kc * 64 + kg * 16) ^ ((row & 7) << 4)));
#pragma unroll
        for (int mr = 0; mr < 2; ++mr)
          acc_o[mr][tt] = __builtin_amdgcn_mfma_f32_16x16x32_bf16(pa[mr], bv, acc_o[mr][tt], 0, 0, 0);
      }
    }
    __syncthreads();
  }

  // epilogue: att[b, s, h*128+d] bf16
  int b = bh >> 3, h = bh & 7;
#pragma unroll
  for (int mr = 0; mr < 2; ++mr)
#pragma unroll
    for (int tt = 0; tt < 8; ++tt)
#pragma unroll
      for (int e = 0; e < 4; ++e) {
        int s = q0 + w * 32 + mr * 16 + kg * 4 + e;
        int d = tt * 16 + lc;
        float v = acc_o[mr][tt][e] / l_run[mr][e];
        att[((b * 2048 + s) * 8 + h) * 128 + d] = f2bf(v);
      }
}

// ---------------- output projection: out = att @ Wo + bo (fp32 out) ----------------
__global__ __launch_bounds__(256) void out_proj_kernel(const unsigned short* __restrict__ att,
    const unsigned short* __restrict__ Wot, const float* __restrict__ bo,
    float* __restrict__ out) {
  __shared__ unsigned short As[64 * 128], Bs[64 * 128];
  int m0 = blockIdx.x * 64, n0 = blockIdx.y * 64;
  int t = threadIdx.x, w = t >> 6, l = t & 63, lc = l & 15, kg = l >> 4;
  f32x4 acc[4];
#pragma unroll
  for (int i = 0; i < 4; ++i) acc[i] = (f32x4){0.f, 0.f, 0.f, 0.f};
  for (int kt = 0; kt < 8; ++kt) {
    if (kt) __syncthreads();
#pragma unroll
    for (int it = 0; it < 4; ++it) {
      int c = t + it * 256;
      int row = c >> 4, col = c & 15;
      *(f32x4*)((char*)As + row * 256 + ((col * 16) ^ ((row & 7) << 4))) =
          *(const f32x4*)(att + (m0 + row) * 1024 + kt * 128 + col * 8);
      *(f32x4*)((char*)Bs + row * 256 + ((col * 16) ^ ((row & 7) << 4))) =
          *(const f32x4*)(Wot + (n0 + row) * 1024 + kt * 128 + col * 8);
    }
    __syncthreads();
    mfma_64x64(As, Bs, w, l, acc);
  }
#pragma unroll
  for (int tt = 0; tt < 4; ++tt)
#pragma unroll
    for (int e = 0; e < 4; ++e) {
      int m = m0 + w * 16 + kg * 4 + e;
      int n = n0 + tt * 16 + lc;
      out[m * 128 + n] = acc[tt][e] + bo[n];
    }
}

extern "C" void kernel_launch(void* const* d_in, const int* in_sizes, int n_in,
                              void* d_out, int out_size, void* d_ws, size_t ws_size,
                              hipStream_t stream) {
  const float* x  = (const float*)d_in[0];
  const float* Wq = (const float*)d_in[1];
  const float* Wk = (const float*)d_in[2];
  const float* Wv = (const float*)d_in[3];
  const float* Wo = (const float*)d_in[4];
  const float* bo = (const float*)d_in[5];
  float* out = (float*)d_out;
  char* ws = (char*)d_ws;
  unsigned short* xb  = (unsigned short*)(ws);
  unsigned short* Wtq = (unsigned short*)(ws + (2u << 20));
  unsigned short* Wtk = (unsigned short*)(ws + (2u << 20) + (256u << 10));
  unsigned short* Wtv = (unsigned short*)(ws + (2u << 20) + (512u << 10));
  unsigned short* Wot = (unsigned short*)(ws + (2u << 20) + (768u << 10));
  unsigned short* Qb  = (unsigned short*)(ws + (3u << 20));
  unsigned short* Kb  = (unsigned short*)(ws + (3u << 20) + (16u << 20));
  unsigned short* Vt  = (unsigned short*)(ws + (3u << 20) + (32u << 20));
  unsigned short* att = (unsigned short*)(ws + (3u << 20) + (48u << 20));

  hipLaunchKernelGGL(prep_kernel, dim3(4096), dim3(256), 0, stream,
                     x, Wq, Wk, Wv, Wo, xb, Wtq, Wtk, Wtv, Wot);
  hipLaunchKernelGGL(proj_qk_kernel, dim3(128, 16, 2), dim3(256), 0, stream,
                     xb, Wtq, Wtk, Qb, Kb);
  hipLaunchKernelGGL(proj_v_kernel, dim3(16, 128), dim3(256), 0, stream,
                     xb, Wtv, Vt);
  hipLaunchKernelGGL(attn_kernel, dim3(16, 32), dim3(256), 0, stream,
                     Qb, Kb, Vt, att);
  hipLaunchKernelGGL(out_proj_kernel, dim3(128, 2), dim3(256), 0, stream,
                     att, Wot, bo, out);
}

// Round 2
// 197.166 us; speedup vs baseline: 2.5541x; 2.5541x over previous
//
#include <hip/hip_runtime.h>

// MHSA fused pipeline: B=4 S=2048 D=128 H=8. fp32 in/out, bf16 MFMA internally.
// ws layout: xb(2MB) Wtq/Wtk/Wtv/Wot(256KB ea) | Qb(16MB) Kb(16MB) Vt(16MB) att(16MB)

typedef __attribute__((ext_vector_type(8))) short bf16x8;
typedef __attribute__((ext_vector_type(4))) float f32x4;
typedef __attribute__((ext_vector_type(16))) float f32x16;
typedef __attribute__((ext_vector_type(4))) int i32x4;

#define LOG2E 1.4426950408889634f

__device__ __forceinline__ unsigned short f2bf(float f) {
  unsigned u = __builtin_bit_cast(unsigned, f);
  return (unsigned short)((u + 0x7fffu + ((u >> 16) & 1u)) >> 16);
}

__device__ __forceinline__ unsigned cvtpk(float lo, float hi) {
  unsigned r;
  asm("v_cvt_pk_bf16_f32 %0, %1, %2" : "=v"(r) : "v"(lo), "v"(hi));
  return r;
}

// ---------------- prep: convert x to bf16, transpose weights ----------------
__global__ void prep_kernel(const float* __restrict__ x, const float* __restrict__ Wq,
                            const float* __restrict__ Wk, const float* __restrict__ Wv,
                            const float* __restrict__ Wo,
                            unsigned short* __restrict__ xb, unsigned short* __restrict__ Wtq,
                            unsigned short* __restrict__ Wtk, unsigned short* __restrict__ Wtv,
                            unsigned short* __restrict__ Wot) {
  int tid = blockIdx.x * 256 + threadIdx.x;
  if (tid < 8192 * 128) xb[tid] = f2bf(x[tid]);
  if (tid < 1024 * 128) {
    int r = tid >> 7, c = tid & 127;        // Wt[n][k] = W[k][n], W is 128x1024
    Wtq[tid] = f2bf(Wq[c * 1024 + r]);
    Wtk[tid] = f2bf(Wk[c * 1024 + r]);
    Wtv[tid] = f2bf(Wv[c * 1024 + r]);
    int r2 = tid >> 10, c2 = tid & 1023;    // Wot[n][k] = Wo[k][n], Wo is 1024x128
    Wot[tid] = f2bf(Wo[c2 * 128 + r2]);
  }
}

// stage 64 rows x 128 bf16 (row stride 128) into LDS, XOR-swizzled rows of 256B
__device__ __forceinline__ void stage_64x128(unsigned short* dst, const unsigned short* gsrc, int t) {
#pragma unroll
  for (int it = 0; it < 4; ++it) {
    int c = t + it * 256;
    int row = c >> 4, col = c & 15;
    *(f32x4*)((char*)dst + row * 256 + ((col * 16) ^ ((row & 7) << 4))) =
        *(const f32x4*)(gsrc + row * 128 + col * 8);
  }
}

// 64x64 output tile from As(64x128) x Bs(64x128)^T, both swizzled
__device__ __forceinline__ void mfma_64x64(const unsigned short* As, const unsigned short* Bs,
                                           int w, int l, f32x4 acc[4]) {
  int lc = l & 15, kg = l >> 4;
#pragma unroll
  for (int kc = 0; kc < 4; ++kc) {
    int ar = w * 16 + lc;
    bf16x8 a = *(const bf16x8*)((const char*)As + ar * 256 + ((kc * 64 + kg * 16) ^ ((ar & 7) << 4)));
#pragma unroll
    for (int tt = 0; tt < 4; ++tt) {
      int br = tt * 16 + lc;
      bf16x8 b = *(const bf16x8*)((const char*)Bs + br * 256 + ((kc * 64 + kg * 16) ^ ((br & 7) << 4)));
      acc[tt] = __builtin_amdgcn_mfma_f32_16x16x32_bf16(a, b, acc[tt], 0, 0, 0);
    }
  }
}

// ---------------- Q,K projections: out[b,h,s,d] = (x @ W) * 128^-0.25 ----------------
__global__ __launch_bounds__(256) void proj_qk_kernel(const unsigned short* __restrict__ xb,
    const unsigned short* __restrict__ Wtq, const unsigned short* __restrict__ Wtk,
    unsigned short* __restrict__ Qb, unsigned short* __restrict__ Kb) {
  __shared__ unsigned short As[64 * 128], Bs[64 * 128];
  const unsigned short* Wt = blockIdx.z ? Wtk : Wtq;
  unsigned short* Out = blockIdx.z ? Kb : Qb;
  int m0 = blockIdx.x * 64, n0 = blockIdx.y * 64;
  int t = threadIdx.x, w = t >> 6, l = t & 63, lc = l & 15, kg = l >> 4;
  stage_64x128(As, xb + m0 * 128, t);
  stage_64x128(Bs, Wt + n0 * 128, t);
  __syncthreads();
  f32x4 acc[4];
#pragma unroll
  for (int i = 0; i < 4; ++i) acc[i] = (f32x4){0.f, 0.f, 0.f, 0.f};
  mfma_64x64(As, Bs, w, l, acc);
  const float scale = 0.29730177875068026f;  // 128^-0.25
#pragma unroll
  for (int tt = 0; tt < 4; ++tt)
#pragma unroll
    for (int e = 0; e < 4; ++e) {
      int m = m0 + w * 16 + kg * 4 + e;
      int n = n0 + tt * 16 + lc;
      int b = m >> 11, s = m & 2047, h = n >> 7, d = n & 127;
      Out[((b * 8 + h) * 2048 + s) * 128 + d] = f2bf(acc[tt][e] * scale);
    }
}

// ---------------- V projection, transposed: Vt[b,h,d,s] = (x @ Wv)^T ----------------
__global__ __launch_bounds__(256) void proj_v_kernel(const unsigned short* __restrict__ xb,
    const unsigned short* __restrict__ Wtv, unsigned short* __restrict__ Vt) {
  __shared__ unsigned short As[64 * 128], Bs[64 * 128];
  int n0 = blockIdx.x * 64;  // rows of Wv^T (n = h*128+d)
  int t0 = blockIdx.y * 64;  // tokens
  int t = threadIdx.x, w = t >> 6, l = t & 63, lc = l & 15, kg = l >> 4;
  stage_64x128(As, Wtv + n0 * 128, t);
  stage_64x128(Bs, xb + t0 * 128, t);
  __syncthreads();
  f32x4 acc[4];
#pragma unroll
  for (int i = 0; i < 4; ++i) acc[i] = (f32x4){0.f, 0.f, 0.f, 0.f};
  mfma_64x64(As, Bs, w, l, acc);
#pragma unroll
  for (int tt = 0; tt < 4; ++tt)
#pragma unroll
    for (int e = 0; e < 4; ++e) {
      int n = n0 + w * 16 + kg * 4 + e;
      int m = t0 + tt * 16 + lc;
      int b = m >> 11, s = m & 2047, h = n >> 7, d = n & 127;
      Vt[((b * 8 + h) * 128 + d) * 2048 + s] = f2bf(acc[tt][e]);
    }
}

// ---------------- flash attention: swapped-QK 32x32 MFMA, 4 waves x 32 q-rows ----------------
// Per wave: 32 q rows, KV tile 64. S^T = mfma(K, Q): lane holds P[q=lane&31][16 kv] per subtile.
// Softmax fully in-register (one shfl_xor(32) per reduce). P packed to PV A-frags via
// cvt_pk + half-exchange. O accumulated as D[q=crow(r,hi)][dd=dt*32+lane&31].
__global__ __launch_bounds__(256, 2) void attn_kernel(const unsigned short* __restrict__ Qb,
    const unsigned short* __restrict__ Kb, const unsigned short* __restrict__ Vt,
    unsigned short* __restrict__ att) {
  __shared__ unsigned short lds[2][16384];  // per buf: K 64x128 (8192) + V^T 128x64 (8192) = 32KB
  int bid = blockIdx.x;
  int fid = (bid & 7) * 64 + (bid >> 3);    // XCD swizzle (512 % 8 == 0 -> bijective)
  int bh = fid >> 4, qt = fid & 15;
  const unsigned short* Qp = Qb + bh * 2048 * 128;
  const unsigned short* Kp = Kb + bh * 2048 * 128;
  const unsigned short* Vp = Vt + bh * 128 * 2048;
  int t = threadIdx.x, w = t >> 6, l = t & 63, lc = l & 31, hi = l >> 5;
  int q0 = qt * 128 + w * 32;

  // Q fragments (B-operand): lane l -> Q[q0+lc][kc*16 + hi*8 + j], direct from global
  bf16x8 qf[8];
  {
    const unsigned short* qr_ = Qp + (q0 + lc) * 128 + hi * 8;
#pragma unroll
    for (int kc = 0; kc < 8; ++kc) qf[kc] = *(const bf16x8*)(qr_ + kc * 16);
  }

  // staging geometry: wave w stages K rows [16w,16w+16), V^T rows [32w,32w+32)
  int kcol = l & 15, vc = l & 7;
  int krow[4], vrow[4];
#pragma unroll
  for (int i = 0; i < 4; ++i) { krow[i] = w * 16 + i * 4 + (l >> 4); vrow[i] = w * 32 + i * 8 + (l >> 3); }

  f32x16 acc[4];
#pragma unroll
  for (int i = 0; i < 4; ++i)
#pragma unroll
    for (int j = 0; j < 16; ++j) acc[i][j] = 0.f;
  float m_run = -1e30f, l_run = 0.f;

  f32x4 sk[4], sv[4];
#pragma unroll
  for (int i = 0; i < 4; ++i) {
    sk[i] = *(const f32x4*)(Kp + krow[i] * 128 + kcol * 8);
    sv[i] = *(const f32x4*)(Vp + vrow[i] * 2048 + vc * 8);
  }
#pragma unroll
  for (int i = 0; i < 4; ++i) {
    *(f32x4*)((char*)&lds[0][0] + krow[i] * 256 + ((kcol * 16) ^ ((krow[i] & 7) << 4))) = sk[i];
    *(f32x4*)((char*)&lds[0][8192] + vrow[i] * 128 + ((vc * 16) ^ ((vrow[i] & 7) << 4))) = sv[i];
  }
  __syncthreads();

  for (int kt = 0; kt < 32; ++kt) {
    int cur = kt & 1;
    if (kt < 31) {  // T14: issue next tile's global loads before compute
      int kv0 = (kt + 1) * 64;
#pragma unroll
      for (int i = 0; i < 4; ++i) {
        sk[i] = *(const f32x4*)(Kp + (kv0 + krow[i]) * 128 + kcol * 8);
        sv[i] = *(const f32x4*)(Vp + vrow[i] * 2048 + kv0 + vc * 8);
      }
    }
    const char* Kb_ = (const char*)&lds[cur][0];
    const char* Vb_ = (const char*)&lds[cur][8192];

    // QK^T swapped: S^T[kv][q] over 2 kv-subtiles of 32
    f32x16 s0, s1;
#pragma unroll
    for (int j = 0; j < 16; ++j) { s0[j] = 0.f; s1[j] = 0.f; }
#pragma unroll
    for (int kc = 0; kc < 8; ++kc) {
      int cb = kc * 32 + hi * 16;
      int r1 = 32 + lc;
      bf16x8 k0 = *(const bf16x8*)(Kb_ + lc * 256 + (cb ^ ((lc & 7) << 4)));
      bf16x8 k1 = *(const bf16x8*)(Kb_ + r1 * 256 + (cb ^ ((r1 & 7) << 4)));
      s0 = __builtin_amdgcn_mfma_f32_32x32x16_bf16(k0, qf[kc], s0, 0, 0, 0);
      s1 = __builtin_amdgcn_mfma_f32_32x32x16_bf16(k1, qf[kc], s1, 0, 0, 0);
    }

    // online softmax, in-register: lane owns q=lc row, half the kv entries
    float pmax = s0[0];
#pragma unroll
    for (int j = 1; j < 16; ++j) pmax = fmaxf(pmax, s0[j]);
#pragma unroll
    for (int j = 0; j < 16; ++j) pmax = fmaxf(pmax, s1[j]);
    pmax = fmaxf(pmax, __shfl_xor(pmax, 32));
    float mold = m_run;
    bool defer = __all(pmax <= m_run + 8.f) != 0;   // T13 defer-max
    if (!defer) m_run = fmaxf(m_run, pmax);
    float rs = 0.f;
#pragma unroll
    for (int j = 0; j < 16; ++j) { s0[j] = __builtin_exp2f((s0[j] - m_run) * LOG2E); rs += s0[j]; }
#pragma unroll
    for (int j = 0; j < 16; ++j) { s1[j] = __builtin_exp2f((s1[j] - m_run) * LOG2E); rs += s1[j]; }
    rs += __shfl_xor(rs, 32);
    if (!defer) {
      float resc = __builtin_exp2f((mold - m_run) * LOG2E);
      l_run = l_run * resc + rs;
#pragma unroll
      for (int r = 0; r < 16; ++r) {
        int qr = (r & 3) + 8 * (r >> 2) + 4 * hi;
        float f = __shfl(resc, qr, 32);
#pragma unroll
        for (int dt = 0; dt < 4; ++dt) acc[dt][r] *= f;
      }
    } else {
      l_run += rs;
    }

    // pack P -> PV A-frags: lane l needs P[q=lc][ks*16 + 8*hi + 0..7]
    bf16x8 pa[4];
#define PACK(ks, SX, o) { \
      unsigned a1 = cvtpk(SX[o], SX[(o) + 1]); \
      unsigned b1 = cvtpk(SX[(o) + 4], SX[(o) + 5]); \
      unsigned a2 = cvtpk(SX[(o) + 2], SX[(o) + 3]); \
      unsigned b2 = cvtpk(SX[(o) + 6], SX[(o) + 7]); \
      unsigned pa1 = (unsigned)__shfl_xor((int)a1, 32), pb1 = (unsigned)__shfl_xor((int)b1, 32); \
      unsigned pa2 = (unsigned)__shfl_xor((int)a2, 32), pb2 = (unsigned)__shfl_xor((int)b2, 32); \
      i32x4 pp; \
      pp[0] = (int)(hi ? pb1 : a1); pp[1] = (int)(hi ? pb2 : a2); \
      pp[2] = (int)(hi ? b1 : pa1); pp[3] = (int)(hi ? b2 : pa2); \
      pa[ks] = __builtin_bit_cast(bf16x8, pp); }
    PACK(0, s0, 0) PACK(1, s0, 8) PACK(2, s1, 0) PACK(3, s1, 8)
#undef PACK

    // PV: acc[dt] += P(32q x 16kv) @ V(16kv x 32dd), V^T rows from LDS
#pragma unroll
    for (int ks = 0; ks < 4; ++ks) {
      int cb = ks * 32 + hi * 16;
#pragma unroll
      for (int dt = 0; dt < 4; ++dt) {
        int vr = dt * 32 + lc;
        bf16x8 vb = *(const bf16x8*)(Vb_ + vr * 128 + (cb ^ ((vr & 7) << 4)));
        acc[dt] = __builtin_amdgcn_mfma_f32_32x32x16_bf16(pa[ks], vb, acc[dt], 0, 0, 0);
      }
    }

    if (kt < 31) {  // write staged tile into other buffer (its readers finished at barrier kt-1)
      char* Kn = (char*)&lds[cur ^ 1][0];
      char* Vn = (char*)&lds[cur ^ 1][8192];
#pragma unroll
      for (int i = 0; i < 4; ++i) {
        *(f32x4*)(Kn + krow[i] * 256 + ((kcol * 16) ^ ((krow[i] & 7) << 4))) = sk[i];
        *(f32x4*)(Vn + vrow[i] * 128 + ((vc * 16) ^ ((vrow[i] & 7) << 4))) = sv[i];
      }
    }
    __syncthreads();
  }

  // epilogue: O[q=crow(r,hi)][dd=dt*32+lc] / l_run[q] -> att[b, s, h*128+dd] (bf16)
  int b = bh >> 3, h = bh & 7;
#pragma unroll
  for (int r = 0; r < 16; ++r) {
    int qr = (r & 3) + 8 * (r >> 2) + 4 * hi;
    float linv = 1.f / __shfl(l_run, qr, 32);
    unsigned short* orow = att + ((b * 2048 + (q0 + qr)) * 8 + h) * 128 + lc;
#pragma unroll
    for (int dt = 0; dt < 4; ++dt) orow[dt * 32] = f2bf(acc[dt][r] * linv);
  }
}

// ---------------- output projection: out = att @ Wo + bo (fp32 out) ----------------
__global__ __launch_bounds__(256) void out_proj_kernel(const unsigned short* __restrict__ att,
    const unsigned short* __restrict__ Wot, const float* __restrict__ bo,
    float* __restrict__ out) {
  __shared__ unsigned short As[64 * 128], Bs[64 * 128];
  int m0 = blockIdx.x * 64, n0 = blockIdx.y * 64;
  int t = threadIdx.x, w = t >> 6, l = t & 63, lc = l & 15, kg = l >> 4;
  f32x4 acc[4];
#pragma unroll
  for (int i = 0; i < 4; ++i) acc[i] = (f32x4){0.f, 0.f, 0.f, 0.f};
  for (int kt = 0; kt < 8; ++kt) {
    if (kt) __syncthreads();
#pragma unroll
    for (int it = 0; it < 4; ++it) {
      int c = t + it * 256;
      int row = c >> 4, col = c & 15;
      *(f32x4*)((char*)As + row * 256 + ((col * 16) ^ ((row & 7) << 4))) =
          *(const f32x4*)(att + (m0 + row) * 1024 + kt * 128 + col * 8);
      *(f32x4*)((char*)Bs + row * 256 + ((col * 16) ^ ((row & 7) << 4))) =
          *(const f32x4*)(Wot + (n0 + row) * 1024 + kt * 128 + col * 8);
    }
    __syncthreads();
    mfma_64x64(As, Bs, w, l, acc);
  }
#pragma unroll
  for (int tt = 0; tt < 4; ++tt)
#pragma unroll
    for (int e = 0; e < 4; ++e) {
      int m = m0 + w * 16 + kg * 4 + e;
      int n = n0 + tt * 16 + lc;
      out[m * 128 + n] = acc[tt][e] + bo[n];
    }
}

extern "C" void kernel_launch(void* const* d_in, const int* in_sizes, int n_in,
                              void* d_out, int out_size, void* d_ws, size_t ws_size,
                              hipStream_t stream) {
  const float* x  = (const float*)d_in[0];
  const float* Wq = (const float*)d_in[1];
  const float* Wk = (const float*)d_in[2];
  const float* Wv = (const float*)d_in[3];
  const float* Wo = (const float*)d_in[4];
  const float* bo = (const float*)d_in[5];
  float* out = (float*)d_out;
  char* ws = (char*)d_ws;
  unsigned short* xb  = (unsigned short*)(ws);
  unsigned short* Wtq = (unsigned short*)(ws + (2u << 20));
  unsigned short* Wtk = (unsigned short*)(ws + (2u << 20) + (256u << 10));
  unsigned short* Wtv = (unsigned short*)(ws + (2u << 20) + (512u << 10));
  unsigned short* Wot = (unsigned short*)(ws + (2u << 20) + (768u << 10));
  unsigned short* Qb  = (unsigned short*)(ws + (3u << 20));
  unsigned short* Kb  = (unsigned short*)(ws + (3u << 20) + (16u << 20));
  unsigned short* Vt  = (unsigned short*)(ws + (3u << 20) + (32u << 20));
  unsigned short* att = (unsigned short*)(ws + (3u << 20) + (48u << 20));

  hipLaunchKernelGGL(prep_kernel, dim3(4096), dim3(256), 0, stream,
                     x, Wq, Wk, Wv, Wo, xb, Wtq, Wtk, Wtv, Wot);
  hipLaunchKernelGGL(proj_qk_kernel, dim3(128, 16, 2), dim3(256), 0, stream,
                     xb, Wtq, Wtk, Qb, Kb);
  hipLaunchKernelGGL(proj_v_kernel, dim3(16, 128), dim3(256), 0, stream,
                     xb, Wtv, Vt);
  hipLaunchKernelGGL(attn_kernel, dim3(512), dim3(256), 0, stream,
                     Qb, Kb, Vt, att);
  hipLaunchKernelGGL(out_proj_kernel, dim3(128, 2), dim3(256), 0, stream,
                     att, Wot, bo, out);
}

// Round 3
// 175.836 us; speedup vs baseline: 2.8639x; 1.1213x over previous
//
#include <hip/hip_runtime.h>

// MHSA fused pipeline: B=4 S=2048 D=128 H=8. fp32 in/out, bf16 MFMA internally.
// ws layout: xb(2MB) Wtq/Wtk/Wtv/Wot(256KB ea) | Qb(16MB) Kb(16MB) Vt(16MB) att(16MB)
// Softmax runs in log2 domain: Q projection is pre-scaled by 128^-0.25 * log2(e).

typedef __attribute__((ext_vector_type(8))) short bf16x8;
typedef __attribute__((ext_vector_type(4))) float f32x4;
typedef __attribute__((ext_vector_type(16))) float f32x16;
typedef __attribute__((ext_vector_type(4))) int i32x4;

#define LOG2E 1.4426950408889634f

__device__ __forceinline__ unsigned short f2bf(float f) {
  unsigned u = __builtin_bit_cast(unsigned, f);
  return (unsigned short)((u + 0x7fffu + ((u >> 16) & 1u)) >> 16);
}

__device__ __forceinline__ unsigned cvtpk(float lo, float hi) {
  unsigned r;
  asm("v_cvt_pk_bf16_f32 %0, %1, %2" : "=v"(r) : "v"(lo), "v"(hi));
  return r;
}

__device__ __forceinline__ float vexp2(float x) {  // raw v_exp_f32 (2^x)
  float r;
  asm("v_exp_f32 %0, %1" : "=v"(r) : "v"(x));
  return r;
}

// ---------------- prep: convert x to bf16, transpose weights ----------------
__global__ void prep_kernel(const float* __restrict__ x, const float* __restrict__ Wq,
                            const float* __restrict__ Wk, const float* __restrict__ Wv,
                            const float* __restrict__ Wo,
                            unsigned short* __restrict__ xb, unsigned short* __restrict__ Wtq,
                            unsigned short* __restrict__ Wtk, unsigned short* __restrict__ Wtv,
                            unsigned short* __restrict__ Wot) {
  int tid = blockIdx.x * 256 + threadIdx.x;
  if (tid < 8192 * 128) xb[tid] = f2bf(x[tid]);
  if (tid < 1024 * 128) {
    int r = tid >> 7, c = tid & 127;        // Wt[n][k] = W[k][n], W is 128x1024
    Wtq[tid] = f2bf(Wq[c * 1024 + r]);
    Wtk[tid] = f2bf(Wk[c * 1024 + r]);
    Wtv[tid] = f2bf(Wv[c * 1024 + r]);
    int r2 = tid >> 10, c2 = tid & 1023;    // Wot[n][k] = Wo[k][n], Wo is 1024x128
    Wot[tid] = f2bf(Wo[c2 * 128 + r2]);
  }
}

// ---------------- shared staging helpers (row = 128 bf16 = 256B swizzled) ----------------
__device__ __forceinline__ void prefetch8(f32x4* r, const unsigned short* gsrc, int t) {
#pragma unroll
  for (int it = 0; it < 8; ++it) {
    int c = t + it * 256, row = c >> 4, col = c & 15;
    r[it] = *(const f32x4*)(gsrc + row * 128 + col * 8);
  }
}

__device__ __forceinline__ void write8(unsigned short* dst, const f32x4* r, int t) {
#pragma unroll
  for (int it = 0; it < 8; ++it) {
    int c = t + it * 256, row = c >> 4, col = c & 15;
    *(f32x4*)((char*)dst + row * 256 + ((col * 16) ^ ((row & 7) << 4))) = r[it];
  }
}

__device__ __forceinline__ void stage_128x128(unsigned short* dst, const unsigned short* gsrc, int t) {
#pragma unroll
  for (int it = 0; it < 8; ++it) {
    int c = t + it * 256, row = c >> 4, col = c & 15;
    *(f32x4*)((char*)dst + row * 256 + ((col * 16) ^ ((row & 7) << 4))) =
        *(const f32x4*)(gsrc + row * 128 + col * 8);
  }
}

// 128x128 tile: 4 waves in 2x2 quadrants, each wave 64x64 (4x4 frags), K=128
__device__ __forceinline__ void mma128(const unsigned short* As, const unsigned short* Bs,
                                       int wm, int wn, int l, f32x4 acc[4][4]) {
  int lc = l & 15, kg = l >> 4;
#pragma unroll
  for (int kc = 0; kc < 4; ++kc) {
    bf16x8 a[4], b[4];
#pragma unroll
    for (int mi = 0; mi < 4; ++mi) {
      int ar = wm * 64 + mi * 16 + lc;
      a[mi] = *(const bf16x8*)((const char*)As + ar * 256 + ((kc * 64 + kg * 16) ^ ((ar & 7) << 4)));
    }
#pragma unroll
    for (int ni = 0; ni < 4; ++ni) {
      int br = wn * 64 + ni * 16 + lc;
      b[ni] = *(const bf16x8*)((const char*)Bs + br * 256 + ((kc * 64 + kg * 16) ^ ((br & 7) << 4)));
    }
#pragma unroll
    for (int mi = 0; mi < 4; ++mi)
#pragma unroll
      for (int ni = 0; ni < 4; ++ni)
        acc[mi][ni] = __builtin_amdgcn_mfma_f32_16x16x32_bf16(a[mi], b[ni], acc[mi][ni], 0, 0, 0);
  }
}

// ---------------- merged QKV projection ----------------
// grid (64, 8): m0 = token tile of 128, n0 = 128 output cols (= one head's d slice)
__global__ __launch_bounds__(256, 2) void qkv_kernel(const unsigned short* __restrict__ xb,
    const unsigned short* __restrict__ Wtq, const unsigned short* __restrict__ Wtk,
    const unsigned short* __restrict__ Wtv,
    unsigned short* __restrict__ Qb, unsigned short* __restrict__ Kb,
    unsigned short* __restrict__ Vt) {
  __shared__ unsigned short Xs[128 * 128], Ws[128 * 128];
  int m0 = blockIdx.x * 128, n0 = blockIdx.y * 128;
  int t = threadIdx.x, w = t >> 6, l = t & 63;
  int wm = w & 1, wn = w >> 1, lc = l & 15, kg = l >> 4;
  stage_128x128(Xs, xb + m0 * 128, t);
  stage_128x128(Ws, Wtq + n0 * 128, t);
  __syncthreads();

  f32x4 rw[8];
  prefetch8(rw, Wtk + n0 * 128, t);   // T14: Wk tile in flight during Q-compute

  f32x4 acc[4][4];
#pragma unroll
  for (int mi = 0; mi < 4; ++mi)
#pragma unroll
    for (int ni = 0; ni < 4; ++ni) acc[mi][ni] = (f32x4){0.f, 0.f, 0.f, 0.f};
  mma128(Xs, Ws, wm, wn, l, acc);
  const float qscale = 0.29730177875068026f * LOG2E;  // 128^-0.25 * log2(e)
#pragma unroll
  for (int mi = 0; mi < 4; ++mi)
#pragma unroll
    for (int ni = 0; ni < 4; ++ni)
#pragma unroll
      for (int e = 0; e < 4; ++e) {
        int m = m0 + wm * 64 + mi * 16 + kg * 4 + e;
        int n = n0 + wn * 64 + ni * 16 + lc;
        int b = m >> 11, s = m & 2047, h = n >> 7, d = n & 127;
        Qb[((b * 8 + h) * 2048 + s) * 128 + d] = f2bf(acc[mi][ni][e] * qscale);
      }
  __syncthreads();
  write8(Ws, rw, t);
  __syncthreads();
  prefetch8(rw, Wtv + n0 * 128, t);   // Wv tile in flight during K-compute

#pragma unroll
  for (int mi = 0; mi < 4; ++mi)
#pragma unroll
    for (int ni = 0; ni < 4; ++ni) acc[mi][ni] = (f32x4){0.f, 0.f, 0.f, 0.f};
  mma128(Xs, Ws, wm, wn, l, acc);
  const float kscale = 0.29730177875068026f;
#pragma unroll
  for (int mi = 0; mi < 4; ++mi)
#pragma unroll
    for (int ni = 0; ni < 4; ++ni)
#pragma unroll
      for (int e = 0; e < 4; ++e) {
        int m = m0 + wm * 64 + mi * 16 + kg * 4 + e;
        int n = n0 + wn * 64 + ni * 16 + lc;
        int b = m >> 11, s = m & 2047, h = n >> 7, d = n & 127;
        Kb[((b * 8 + h) * 2048 + s) * 128 + d] = f2bf(acc[mi][ni][e] * kscale);
      }
  __syncthreads();
  write8(Ws, rw, t);
  __syncthreads();

  // V phase, operand-swapped: A = Wv^T rows (n), B = x rows (m) -> coalesced Vt write
#pragma unroll
  for (int mi = 0; mi < 4; ++mi)
#pragma unroll
    for (int ni = 0; ni < 4; ++ni) acc[mi][ni] = (f32x4){0.f, 0.f, 0.f, 0.f};
  mma128(Ws, Xs, wm, wn, l, acc);
#pragma unroll
  for (int mi = 0; mi < 4; ++mi)
#pragma unroll
    for (int ni = 0; ni < 4; ++ni)
#pragma unroll
      for (int e = 0; e < 4; ++e) {
        int n = n0 + wm * 64 + mi * 16 + kg * 4 + e;
        int m = m0 + wn * 64 + ni * 16 + lc;
        int b = m >> 11, s = m & 2047, h = n >> 7, d = n & 127;
        Vt[((b * 8 + h) * 128 + d) * 2048 + s] = f2bf(acc[mi][ni][e]);
      }
}

// ---------------- flash attention: swapped-QK 32x32 MFMA, 4 waves x 32 q-rows ----------------
__global__ __launch_bounds__(256, 2) void attn_kernel(const unsigned short* __restrict__ Qb,
    const unsigned short* __restrict__ Kb, const unsigned short* __restrict__ Vt,
    unsigned short* __restrict__ att) {
  __shared__ unsigned short lds[2][16384];  // per buf: K 64x128 (16KB) + V^T 128x64 (16KB)
  int bid = blockIdx.x;
  int fid = (bid & 7) * 64 + (bid >> 3);    // XCD swizzle (512 % 8 == 0 -> bijective)
  int bh = fid >> 4, qt = fid & 15;
  const unsigned short* Qp = Qb + bh * 2048 * 128;
  const unsigned short* Kp = Kb + bh * 2048 * 128;
  const unsigned short* Vp = Vt + bh * 128 * 2048;
  int t = threadIdx.x, w = t >> 6, l = t & 63, lc = l & 31, hi = l >> 5;
  int q0 = qt * 128 + w * 32;

  // Q fragments (B-operand): lane l -> Q[q0+lc][kc*16 + hi*8 + j], direct from global
  bf16x8 qf[8];
  {
    const unsigned short* qr_ = Qp + (q0 + lc) * 128 + hi * 8;
#pragma unroll
    for (int kc = 0; kc < 8; ++kc) qf[kc] = *(const bf16x8*)(qr_ + kc * 16);
  }

  // staging geometry: wave w stages K rows [16w,16w+16), V^T rows [32w,32w+32)
  int kcol = l & 15, vc = l & 7;
  int krow[4], vrow[4];
#pragma unroll
  for (int i = 0; i < 4; ++i) { krow[i] = w * 16 + i * 4 + (l >> 4); vrow[i] = w * 32 + i * 8 + (l >> 3); }

  f32x16 acc[4];
#pragma unroll
  for (int i = 0; i < 4; ++i)
#pragma unroll
    for (int j = 0; j < 16; ++j) acc[i][j] = 0.f;
  float m_run = -1e30f, l_run = 0.f;

  f32x4 sk[4], sv[4];
#pragma unroll
  for (int i = 0; i < 4; ++i) {
    sk[i] = *(const f32x4*)(Kp + krow[i] * 128 + kcol * 8);
    sv[i] = *(const f32x4*)(Vp + vrow[i] * 2048 + vc * 8);
  }
#pragma unroll
  for (int i = 0; i < 4; ++i) {
    *(f32x4*)((char*)&lds[0][0] + krow[i] * 256 + ((kcol * 16) ^ ((krow[i] & 7) << 4))) = sk[i];
    *(f32x4*)((char*)&lds[0][8192] + vrow[i] * 128 + ((vc * 16) ^ ((vrow[i] & 7) << 4))) = sv[i];
  }
  __syncthreads();

  for (int kt = 0; kt < 32; ++kt) {
    int cur = kt & 1;
    if (kt < 31) {  // T14: issue next tile's global loads before compute
      int kv0 = (kt + 1) * 64;
#pragma unroll
      for (int i = 0; i < 4; ++i) {
        sk[i] = *(const f32x4*)(Kp + (kv0 + krow[i]) * 128 + kcol * 8);
        sv[i] = *(const f32x4*)(Vp + vrow[i] * 2048 + kv0 + vc * 8);
      }
    }
    const char* Kb_ = (const char*)&lds[cur][0];
    const char* Vb_ = (const char*)&lds[cur][8192];

    // QK^T swapped: S^T[kv][q] over 2 kv-subtiles of 32 (S already in log2 units)
    f32x16 s0, s1;
#pragma unroll
    for (int j = 0; j < 16; ++j) { s0[j] = 0.f; s1[j] = 0.f; }
    __builtin_amdgcn_s_setprio(1);
#pragma unroll
    for (int kc = 0; kc < 8; ++kc) {
      int cb = kc * 32 + hi * 16;
      int r1 = 32 + lc;
      bf16x8 k0 = *(const bf16x8*)(Kb_ + lc * 256 + (cb ^ ((lc & 7) << 4)));
      bf16x8 k1 = *(const bf16x8*)(Kb_ + r1 * 256 + (cb ^ ((r1 & 7) << 4)));
      s0 = __builtin_amdgcn_mfma_f32_32x32x16_bf16(k0, qf[kc], s0, 0, 0, 0);
      s1 = __builtin_amdgcn_mfma_f32_32x32x16_bf16(k1, qf[kc], s1, 0, 0, 0);
    }
    __builtin_amdgcn_s_setprio(0);

    // online softmax (log2 domain), tree reductions (no 31-deep serial chains)
    float t8[8];
#pragma unroll
    for (int j = 0; j < 8; ++j)
      t8[j] = fmaxf(fmaxf(s0[j], s0[j + 8]), fmaxf(s1[j], s1[j + 8]));
    float pmax = fmaxf(fmaxf(fmaxf(t8[0], t8[1]), fmaxf(t8[2], t8[3])),
                       fmaxf(fmaxf(t8[4], t8[5]), fmaxf(t8[6], t8[7])));
    pmax = fmaxf(pmax, __shfl_xor(pmax, 32));
    float mold = m_run;
    bool defer = (__all(pmax <= m_run + 11.5416f) != 0);   // T13: e^8 bound in log2 units
    if (!defer) m_run = fmaxf(m_run, pmax);
#pragma unroll
    for (int j = 0; j < 16; ++j) s0[j] = vexp2(s0[j] - m_run);
#pragma unroll
    for (int j = 0; j < 16; ++j) s1[j] = vexp2(s1[j] - m_run);
    float q8[8];
#pragma unroll
    for (int j = 0; j < 8; ++j)
      q8[j] = (s0[j] + s0[j + 8]) + (s1[j] + s1[j + 8]);
    float rs = ((q8[0] + q8[1]) + (q8[2] + q8[3])) + ((q8[4] + q8[5]) + (q8[6] + q8[7]));
    rs += __shfl_xor(rs, 32);
    if (!defer) {
      float resc = vexp2(mold - m_run);
      l_run = l_run * resc + rs;
#pragma unroll
      for (int r = 0; r < 16; ++r) {
        int qr = (r & 3) + 8 * (r >> 2) + 4 * hi;
        float f = __shfl(resc, qr, 32);
#pragma unroll
        for (int dt = 0; dt < 4; ++dt) acc[dt][r] *= f;
      }
    } else {
      l_run += rs;
    }

    // pack P -> PV A-frags via cvt_pk + permlane32_swap (T12)
    bf16x8 pa[4];
#define PACK(ks, SX, o) { \
      unsigned x1 = cvtpk(SX[o], SX[(o) + 1]); \
      unsigned y1 = cvtpk(SX[(o) + 4], SX[(o) + 5]); \
      unsigned x2 = cvtpk(SX[(o) + 2], SX[(o) + 3]); \
      unsigned y2 = cvtpk(SX[(o) + 6], SX[(o) + 7]); \
      asm("v_permlane32_swap_b32 %0, %1" : "+v"(x1), "+v"(y1)); \
      asm("v_permlane32_swap_b32 %0, %1" : "+v"(x2), "+v"(y2)); \
      i32x4 pp; \
      pp[0] = (int)x1; pp[1] = (int)x2; pp[2] = (int)y1; pp[3] = (int)y2; \
      pa[ks] = __builtin_bit_cast(bf16x8, pp); }
    PACK(0, s0, 0) PACK(1, s0, 8) PACK(2, s1, 0) PACK(3, s1, 8)
#undef PACK

    // PV: acc[dt] += P(32q x 16kv) @ V(16kv x 32dd), V^T rows from LDS
    __builtin_amdgcn_s_setprio(1);
#pragma unroll
    for (int ks = 0; ks < 4; ++ks) {
      int cb = ks * 32 + hi * 16;
#pragma unroll
      for (int dt = 0; dt < 4; ++dt) {
        int vr = dt * 32 + lc;
        bf16x8 vb = *(const bf16x8*)(Vb_ + vr * 128 + (cb ^ ((vr & 7) << 4)));
        acc[dt] = __builtin_amdgcn_mfma_f32_32x32x16_bf16(pa[ks], vb, acc[dt], 0, 0, 0);
      }
    }
    __builtin_amdgcn_s_setprio(0);

    if (kt < 31) {  // write staged tile into other buffer (its readers finished at barrier kt-1)
      char* Kn = (char*)&lds[cur ^ 1][0];
      char* Vn = (char*)&lds[cur ^ 1][8192];
#pragma unroll
      for (int i = 0; i < 4; ++i) {
        *(f32x4*)(Kn + krow[i] * 256 + ((kcol * 16) ^ ((krow[i] & 7) << 4))) = sk[i];
        *(f32x4*)(Vn + vrow[i] * 128 + ((vc * 16) ^ ((vrow[i] & 7) << 4))) = sv[i];
      }
    }
    __syncthreads();
  }

  // epilogue: O[q=crow(r,hi)][dd=dt*32+lc] / l_run[q] -> att[b, s, h*128+dd] (bf16)
  int b = bh >> 3, h = bh & 7;
#pragma unroll
  for (int r = 0; r < 16; ++r) {
    int qr = (r & 3) + 8 * (r >> 2) + 4 * hi;
    float linv = 1.f / __shfl(l_run, qr, 32);
    unsigned short* orow = att + ((b * 2048 + (q0 + qr)) * 8 + h) * 128 + lc;
#pragma unroll
    for (int dt = 0; dt < 4; ++dt) orow[dt * 32] = f2bf(acc[dt][r] * linv);
  }
}

// 64x64 output tile from As(64x128) x Bs(64x128)^T, both swizzled
__device__ __forceinline__ void mfma_64x64(const unsigned short* As, const unsigned short* Bs,
                                           int w, int l, f32x4 acc[4]) {
  int lc = l & 15, kg = l >> 4;
#pragma unroll
  for (int kc = 0; kc < 4; ++kc) {
    int ar = w * 16 + lc;
    bf16x8 a = *(const bf16x8*)((const char*)As + ar * 256 + ((kc * 64 + kg * 16) ^ ((ar & 7) << 4)));
#pragma unroll
    for (int tt = 0; tt < 4; ++tt) {
      int br = tt * 16 + lc;
      bf16x8 b = *(const bf16x8*)((const char*)Bs + br * 256 + ((kc * 64 + kg * 16) ^ ((br & 7) << 4)));
      acc[tt] = __builtin_amdgcn_mfma_f32_16x16x32_bf16(a, b, acc[tt], 0, 0, 0);
    }
  }
}

// ---------------- output projection: out = att @ Wo + bo (fp32 out) ----------------
__global__ __launch_bounds__(256) void out_proj_kernel(const unsigned short* __restrict__ att,
    const unsigned short* __restrict__ Wot, const float* __restrict__ bo,
    float* __restrict__ out) {
  __shared__ unsigned short As[64 * 128], Bs[64 * 128];
  int m0 = blockIdx.x * 64, n0 = blockIdx.y * 64;
  int t = threadIdx.x, w = t >> 6, l = t & 63, lc = l & 15, kg = l >> 4;
  f32x4 acc[4];
#pragma unroll
  for (int i = 0; i < 4; ++i) acc[i] = (f32x4){0.f, 0.f, 0.f, 0.f};
  f32x4 ra[4], rb[4];
#pragma unroll
  for (int it = 0; it < 4; ++it) {
    int c = t + it * 256, row = c >> 4, col = c & 15;
    ra[it] = *(const f32x4*)(att + (m0 + row) * 1024 + col * 8);
    rb[it] = *(const f32x4*)(Wot + (n0 + row) * 1024 + col * 8);
  }
  for (int kt = 0; kt < 8; ++kt) {
    if (kt) __syncthreads();
#pragma unroll
    for (int it = 0; it < 4; ++it) {
      int c = t + it * 256, row = c >> 4, col = c & 15;
      *(f32x4*)((char*)As + row * 256 + ((col * 16) ^ ((row & 7) << 4))) = ra[it];
      *(f32x4*)((char*)Bs + row * 256 + ((col * 16) ^ ((row & 7) << 4))) = rb[it];
    }
    __syncthreads();
    if (kt < 7) {
#pragma unroll
      for (int it = 0; it < 4; ++it) {
        int c = t + it * 256, row = c >> 4, col = c & 15;
        ra[it] = *(const f32x4*)(att + (m0 + row) * 1024 + (kt + 1) * 128 + col * 8);
        rb[it] = *(const f32x4*)(Wot + (n0 + row) * 1024 + (kt + 1) * 128 + col * 8);
      }
    }
    mfma_64x64(As, Bs, w, l, acc);
  }
#pragma unroll
  for (int tt = 0; tt < 4; ++tt)
#pragma unroll
    for (int e = 0; e < 4; ++e) {
      int m = m0 + w * 16 + kg * 4 + e;
      int n = n0 + tt * 16 + lc;
      out[m * 128 + n] = acc[tt][e] + bo[n];
    }
}

extern "C" void kernel_launch(void* const* d_in, const int* in_sizes, int n_in,
                              void* d_out, int out_size, void* d_ws, size_t ws_size,
                              hipStream_t stream) {
  const float* x  = (const float*)d_in[0];
  const float* Wq = (const float*)d_in[1];
  const float* Wk = (const float*)d_in[2];
  const float* Wv = (const float*)d_in[3];
  const float* Wo = (const float*)d_in[4];
  const float* bo = (const float*)d_in[5];
  float* out = (float*)d_out;
  char* ws = (char*)d_ws;
  unsigned short* xb  = (unsigned short*)(ws);
  unsigned short* Wtq = (unsigned short*)(ws + (2u << 20));
  unsigned short* Wtk = (unsigned short*)(ws + (2u << 20) + (256u << 10));
  unsigned short* Wtv = (unsigned short*)(ws + (2u << 20) + (512u << 10));
  unsigned short* Wot = (unsigned short*)(ws + (2u << 20) + (768u << 10));
  unsigned short* Qb  = (unsigned short*)(ws + (3u << 20));
  unsigned short* Kb  = (unsigned short*)(ws + (3u << 20) + (16u << 20));
  unsigned short* Vt  = (unsigned short*)(ws + (3u << 20) + (32u << 20));
  unsigned short* att = (unsigned short*)(ws + (3u << 20) + (48u << 20));

  hipLaunchKernelGGL(prep_kernel, dim3(4096), dim3(256), 0, stream,
                     x, Wq, Wk, Wv, Wo, xb, Wtq, Wtk, Wtv, Wot);
  hipLaunchKernelGGL(qkv_kernel, dim3(64, 8), dim3(256), 0, stream,
                     xb, Wtq, Wtk, Wtv, Qb, Kb, Vt);
  hipLaunchKernelGGL(attn_kernel, dim3(512), dim3(256), 0, stream,
                     Qb, Kb, Vt, att);
  hipLaunchKernelGGL(out_proj_kernel, dim3(128, 2), dim3(256), 0, stream,
                     att, Wot, bo, out);
}

// Round 4
// 167.130 us; speedup vs baseline: 3.0131x; 1.0521x over previous
//
#include <hip/hip_runtime.h>

// MHSA fused pipeline: B=4 S=2048 D=128 H=8. fp32 in/out, bf16 MFMA internally.
// ws layout: xb(2MB) Wtq/Wtk/Wtv/Wot(256KB ea) | Qb(16MB) Kb(16MB) Vt(16MB) att(16MB)
// Softmax runs in log2 domain: Q projection is pre-scaled by 128^-0.25 * log2(e).

typedef __attribute__((ext_vector_type(8))) short bf16x8;
typedef __attribute__((ext_vector_type(4))) float f32x4;
typedef __attribute__((ext_vector_type(16))) float f32x16;
typedef __attribute__((ext_vector_type(4))) int i32x4;

#define LOG2E 1.4426950408889634f

__device__ __forceinline__ unsigned short f2bf(float f) {
  unsigned u = __builtin_bit_cast(unsigned, f);
  return (unsigned short)((u + 0x7fffu + ((u >> 16) & 1u)) >> 16);
}

__device__ __forceinline__ unsigned cvtpk(float lo, float hi) {
  unsigned r;
  asm("v_cvt_pk_bf16_f32 %0, %1, %2" : "=v"(r) : "v"(lo), "v"(hi));
  return r;
}

__device__ __forceinline__ float vexp2(float x) {  // raw v_exp_f32 (2^x)
  float r;
  asm("v_exp_f32 %0, %1" : "=v"(r) : "v"(x));
  return r;
}

// ---------------- prep: x -> bf16 (vectorized); W transposes via LDS tiles ----------------
// grid 640: [0,512) x-convert; [512,640) = 4 weights x 32 tile-blocks of 64x64
__global__ __launch_bounds__(256) void prep_kernel(const float* __restrict__ x,
    const float* __restrict__ Wq, const float* __restrict__ Wk, const float* __restrict__ Wv,
    const float* __restrict__ Wo,
    unsigned short* __restrict__ xb, unsigned short* __restrict__ Wtq,
    unsigned short* __restrict__ Wtk, unsigned short* __restrict__ Wtv,
    unsigned short* __restrict__ Wot) {
  __shared__ float tl[64][68];
  int bid = blockIdx.x, t = threadIdx.x;
  if (bid < 512) {
    int idx = (bid * 256 + t) * 8;
    f32x4 a = *(const f32x4*)(x + idx);
    f32x4 b = *(const f32x4*)(x + idx + 4);
    i32x4 o;
    o[0] = (int)cvtpk(a[0], a[1]); o[1] = (int)cvtpk(a[2], a[3]);
    o[2] = (int)cvtpk(b[0], b[1]); o[3] = (int)cvtpk(b[2], b[3]);
    *(i32x4*)(xb + idx) = o;
    return;
  }
  int tb = bid - 512;
  int which = tb >> 5, tile = tb & 31;
  const float* in; unsigned short* out; int K, N, kt_, nt_;
  if (which == 0)      { in = Wq; out = Wtq; }
  else if (which == 1) { in = Wk; out = Wtk; }
  else if (which == 2) { in = Wv; out = Wtv; }
  else                 { in = Wo; out = Wot; }
  if (which < 3) { K = 128;  N = 1024; kt_ = tile >> 4; nt_ = tile & 15; }
  else           { K = 1024; N = 128;  kt_ = tile >> 1; nt_ = tile & 1; }
  int k0 = kt_ * 64, n0 = nt_ * 64;
  int tr = t >> 4, tc = (t & 15) * 4;
#pragma unroll
  for (int i = 0; i < 4; ++i) {
    f32x4 v = *(const f32x4*)(in + (k0 + tr + i * 16) * N + n0 + tc);
#pragma unroll
    for (int j = 0; j < 4; ++j) tl[tc + j][tr + i * 16] = v[j];
  }
  __syncthreads();
  int n = t >> 2, c0 = (t & 3) * 16;
  i32x4 o1, o2;
#pragma unroll
  for (int j = 0; j < 4; ++j) o1[j] = (int)cvtpk(tl[n][c0 + 2 * j], tl[n][c0 + 2 * j + 1]);
#pragma unroll
  for (int j = 0; j < 4; ++j) o2[j] = (int)cvtpk(tl[n][c0 + 8 + 2 * j], tl[n][c0 + 9 + 2 * j]);
  *(i32x4*)(out + (n0 + n) * K + k0 + c0) = o1;
  *(i32x4*)(out + (n0 + n) * K + k0 + c0 + 8) = o2;
}

// ---------------- shared staging helpers (row = 128 bf16 = 256B swizzled) ----------------
__device__ __forceinline__ void prefetch8(f32x4* r, const unsigned short* gsrc, int t) {
#pragma unroll
  for (int it = 0; it < 8; ++it) {
    int c = t + it * 256, row = c >> 4, col = c & 15;
    r[it] = *(const f32x4*)(gsrc + row * 128 + col * 8);
  }
}

__device__ __forceinline__ void write8(unsigned short* dst, const f32x4* r, int t) {
#pragma unroll
  for (int it = 0; it < 8; ++it) {
    int c = t + it * 256, row = c >> 4, col = c & 15;
    *(f32x4*)((char*)dst + row * 256 + ((col * 16) ^ ((row & 7) << 4))) = r[it];
  }
}

__device__ __forceinline__ void stage_128x128(unsigned short* dst, const unsigned short* gsrc, int t) {
#pragma unroll
  for (int it = 0; it < 8; ++it) {
    int c = t + it * 256, row = c >> 4, col = c & 15;
    *(f32x4*)((char*)dst + row * 256 + ((col * 16) ^ ((row & 7) << 4))) =
        *(const f32x4*)(gsrc + row * 128 + col * 8);
  }
}

// 128x128 tile: 4 waves in 2x2 quadrants, each wave 64x64 (4x4 frags), K=128
__device__ __forceinline__ void mma128(const unsigned short* As, const unsigned short* Bs,
                                       int wm, int wn, int l, f32x4 acc[4][4]) {
  int lc = l & 15, kg = l >> 4;
#pragma unroll
  for (int kc = 0; kc < 4; ++kc) {
    bf16x8 a[4], b[4];
#pragma unroll
    for (int mi = 0; mi < 4; ++mi) {
      int ar = wm * 64 + mi * 16 + lc;
      a[mi] = *(const bf16x8*)((const char*)As + ar * 256 + ((kc * 64 + kg * 16) ^ ((ar & 7) << 4)));
    }
#pragma unroll
    for (int ni = 0; ni < 4; ++ni) {
      int br = wn * 64 + ni * 16 + lc;
      b[ni] = *(const bf16x8*)((const char*)Bs + br * 256 + ((kc * 64 + kg * 16) ^ ((br & 7) << 4)));
    }
#pragma unroll
    for (int mi = 0; mi < 4; ++mi)
#pragma unroll
      for (int ni = 0; ni < 4; ++ni)
        acc[mi][ni] = __builtin_amdgcn_mfma_f32_16x16x32_bf16(a[mi], b[ni], acc[mi][ni], 0, 0, 0);
  }
}

// ---------------- merged QKV projection ----------------
__global__ __launch_bounds__(256, 2) void qkv_kernel(const unsigned short* __restrict__ xb,
    const unsigned short* __restrict__ Wtq, const unsigned short* __restrict__ Wtk,
    const unsigned short* __restrict__ Wtv,
    unsigned short* __restrict__ Qb, unsigned short* __restrict__ Kb,
    unsigned short* __restrict__ Vt) {
  __shared__ unsigned short Xs[128 * 128], Ws[128 * 128];
  int m0 = blockIdx.x * 128, n0 = blockIdx.y * 128;
  int t = threadIdx.x, w = t >> 6, l = t & 63;
  int wm = w & 1, wn = w >> 1, lc = l & 15, kg = l >> 4;
  stage_128x128(Xs, xb + m0 * 128, t);
  stage_128x128(Ws, Wtq + n0 * 128, t);
  __syncthreads();

  f32x4 rw[8];
  prefetch8(rw, Wtk + n0 * 128, t);   // T14: Wk tile in flight during Q-compute

  f32x4 acc[4][4];
#pragma unroll
  for (int mi = 0; mi < 4; ++mi)
#pragma unroll
    for (int ni = 0; ni < 4; ++ni) acc[mi][ni] = (f32x4){0.f, 0.f, 0.f, 0.f};
  mma128(Xs, Ws, wm, wn, l, acc);
  const float qscale = 0.29730177875068026f * LOG2E;  // 128^-0.25 * log2(e)
#pragma unroll
  for (int mi = 0; mi < 4; ++mi)
#pragma unroll
    for (int ni = 0; ni < 4; ++ni)
#pragma unroll
      for (int e = 0; e < 4; ++e) {
        int m = m0 + wm * 64 + mi * 16 + kg * 4 + e;
        int n = n0 + wn * 64 + ni * 16 + lc;
        int b = m >> 11, s = m & 2047, h = n >> 7, d = n & 127;
        Qb[((b * 8 + h) * 2048 + s) * 128 + d] = f2bf(acc[mi][ni][e] * qscale);
      }
  __syncthreads();
  write8(Ws, rw, t);
  __syncthreads();
  prefetch8(rw, Wtv + n0 * 128, t);   // Wv tile in flight during K-compute

#pragma unroll
  for (int mi = 0; mi < 4; ++mi)
#pragma unroll
    for (int ni = 0; ni < 4; ++ni) acc[mi][ni] = (f32x4){0.f, 0.f, 0.f, 0.f};
  mma128(Xs, Ws, wm, wn, l, acc);
  const float kscale = 0.29730177875068026f;
#pragma unroll
  for (int mi = 0; mi < 4; ++mi)
#pragma unroll
    for (int ni = 0; ni < 4; ++ni)
#pragma unroll
      for (int e = 0; e < 4; ++e) {
        int m = m0 + wm * 64 + mi * 16 + kg * 4 + e;
        int n = n0 + wn * 64 + ni * 16 + lc;
        int b = m >> 11, s = m & 2047, h = n >> 7, d = n & 127;
        Kb[((b * 8 + h) * 2048 + s) * 128 + d] = f2bf(acc[mi][ni][e] * kscale);
      }
  __syncthreads();
  write8(Ws, rw, t);
  __syncthreads();

  // V phase, operand-swapped: A = Wv^T rows (n), B = x rows (m) -> coalesced Vt write
#pragma unroll
  for (int mi = 0; mi < 4; ++mi)
#pragma unroll
    for (int ni = 0; ni < 4; ++ni) acc[mi][ni] = (f32x4){0.f, 0.f, 0.f, 0.f};
  mma128(Ws, Xs, wm, wn, l, acc);
#pragma unroll
  for (int mi = 0; mi < 4; ++mi)
#pragma unroll
    for (int ni = 0; ni < 4; ++ni)
#pragma unroll
      for (int e = 0; e < 4; ++e) {
        int n = n0 + wm * 64 + mi * 16 + kg * 4 + e;
        int m = m0 + wn * 64 + ni * 16 + lc;
        int b = m >> 11, s = m & 2047, h = n >> 7, d = n & 127;
        Vt[((b * 8 + h) * 128 + d) * 2048 + s] = f2bf(acc[mi][ni][e]);
      }
}

// ---------------- flash attention: T15 double-pipeline, swapped-QK 32x32 MFMA ----------------
// Per iter kt: softmax(kt) | barrier | stage(kt+1) + issue loads(kt+2) | barrier |
//              setprio{ QK(kt+1) + PV(kt) }  -- one contiguous 32-MFMA cluster.
__device__ __forceinline__ void qk_step(const char* Kb_, const bf16x8* qf, int lc, int hi,
                                        f32x16& s0, f32x16& s1) {
#pragma unroll
  for (int j = 0; j < 16; ++j) { s0[j] = 0.f; s1[j] = 0.f; }
  int r1 = 32 + lc;
#pragma unroll
  for (int kc = 0; kc < 8; ++kc) {
    int cb = kc * 32 + hi * 16;
    bf16x8 k0 = *(const bf16x8*)(Kb_ + lc * 256 + (cb ^ ((lc & 7) << 4)));
    bf16x8 k1 = *(const bf16x8*)(Kb_ + r1 * 256 + (cb ^ ((r1 & 7) << 4)));
    s0 = __builtin_amdgcn_mfma_f32_32x32x16_bf16(k0, qf[kc], s0, 0, 0, 0);
    s1 = __builtin_amdgcn_mfma_f32_32x32x16_bf16(k1, qf[kc], s1, 0, 0, 0);
  }
}

__global__ __launch_bounds__(256, 2) void attn_kernel(const unsigned short* __restrict__ Qb,
    const unsigned short* __restrict__ Kb, const unsigned short* __restrict__ Vt,
    unsigned short* __restrict__ att) {
  __shared__ unsigned short lds[2][16384];  // per buf: K 64x128 (16KB) + V^T 128x64 (16KB)
  int bid = blockIdx.x;
  int fid = (bid & 7) * 64 + (bid >> 3);    // XCD swizzle (512 % 8 == 0 -> bijective)
  int bh = fid >> 4, qt = fid & 15;
  const unsigned short* Qp = Qb + bh * 2048 * 128;
  const unsigned short* Kp = Kb + bh * 2048 * 128;
  const unsigned short* Vp = Vt + bh * 128 * 2048;
  int t = threadIdx.x, w = t >> 6, l = t & 63, lc = l & 31, hi = l >> 5;
  int q0 = qt * 128 + w * 32;

  // Q fragments (B-operand): lane l -> Q[q0+lc][kc*16 + hi*8 + j], direct from global
  bf16x8 qf[8];
  {
    const unsigned short* qr_ = Qp + (q0 + lc) * 128 + hi * 8;
#pragma unroll
    for (int kc = 0; kc < 8; ++kc) qf[kc] = *(const bf16x8*)(qr_ + kc * 16);
  }

  // staging geometry: wave w stages K rows [16w,16w+16), V^T rows [32w,32w+32)
  int kcol = l & 15, vc = l & 7;
  int krow[4], vrow[4];
#pragma unroll
  for (int i = 0; i < 4; ++i) { krow[i] = w * 16 + i * 4 + (l >> 4); vrow[i] = w * 32 + i * 8 + (l >> 3); }

  f32x16 acc[4];
#pragma unroll
  for (int i = 0; i < 4; ++i)
#pragma unroll
    for (int j = 0; j < 16; ++j) acc[i][j] = 0.f;
  float m_run = -1e30f, l_run = 0.f;

  f32x4 sk[4], sv[4];
  // prologue: tile 0 -> LDS buf0; tile 1 -> regs; QK(0)
#pragma unroll
  for (int i = 0; i < 4; ++i) {
    sk[i] = *(const f32x4*)(Kp + krow[i] * 128 + kcol * 8);
    sv[i] = *(const f32x4*)(Vp + vrow[i] * 2048 + vc * 8);
  }
#pragma unroll
  for (int i = 0; i < 4; ++i) {
    *(f32x4*)((char*)&lds[0][0] + krow[i] * 256 + ((kcol * 16) ^ ((krow[i] & 7) << 4))) = sk[i];
    *(f32x4*)((char*)&lds[0][8192] + vrow[i] * 128 + ((vc * 16) ^ ((vrow[i] & 7) << 4))) = sv[i];
  }
#pragma unroll
  for (int i = 0; i < 4; ++i) {
    sk[i] = *(const f32x4*)(Kp + (64 + krow[i]) * 128 + kcol * 8);
    sv[i] = *(const f32x4*)(Vp + vrow[i] * 2048 + 64 + vc * 8);
  }
  __syncthreads();
  f32x16 s0, s1;
  qk_step((const char*)&lds[0][0], qf, lc, hi, s0, s1);

  for (int kt = 0; kt < 32; ++kt) {
    int nb = (kt + 1) & 1;

    // ---- softmax(kt) in log2 domain, tree reductions ----
    float t8[8];
#pragma unroll
    for (int j = 0; j < 8; ++j)
      t8[j] = fmaxf(fmaxf(s0[j], s0[j + 8]), fmaxf(s1[j], s1[j + 8]));
    float pmax = fmaxf(fmaxf(fmaxf(t8[0], t8[1]), fmaxf(t8[2], t8[3])),
                       fmaxf(fmaxf(t8[4], t8[5]), fmaxf(t8[6], t8[7])));
    pmax = fmaxf(pmax, __shfl_xor(pmax, 32));
    float mold = m_run;
    bool defer = (__all(pmax <= m_run + 11.5416f) != 0);   // T13: e^8 bound in log2 units
    if (!defer) m_run = fmaxf(m_run, pmax);
#pragma unroll
    for (int j = 0; j < 16; ++j) s0[j] = vexp2(s0[j] - m_run);
#pragma unroll
    for (int j = 0; j < 16; ++j) s1[j] = vexp2(s1[j] - m_run);
    float q8[8];
#pragma unroll
    for (int j = 0; j < 8; ++j)
      q8[j] = (s0[j] + s0[j + 8]) + (s1[j] + s1[j + 8]);
    float rs = ((q8[0] + q8[1]) + (q8[2] + q8[3])) + ((q8[4] + q8[5]) + (q8[6] + q8[7]));
    rs += __shfl_xor(rs, 32);
    if (!defer) {
      float resc = vexp2(mold - m_run);
      l_run = l_run * resc + rs;
#pragma unroll
      for (int r = 0; r < 16; ++r) {
        int qr = (r & 3) + 8 * (r >> 2) + 4 * hi;
        float f = __shfl(resc, qr, 32);
#pragma unroll
        for (int dt = 0; dt < 4; ++dt) acc[dt][r] *= f;
      }
    } else {
      l_run += rs;
    }

    // ---- pack P -> PV A-frags via cvt_pk + permlane32_swap (T12) ----
    bf16x8 pa[4];
#define PACK(ks, SX, o) { \
      unsigned x1 = cvtpk(SX[o], SX[(o) + 1]); \
      unsigned y1 = cvtpk(SX[(o) + 4], SX[(o) + 5]); \
      unsigned x2 = cvtpk(SX[(o) + 2], SX[(o) + 3]); \
      unsigned y2 = cvtpk(SX[(o) + 6], SX[(o) + 7]); \
      asm("v_permlane32_swap_b32 %0, %1" : "+v"(x1), "+v"(y1)); \
      asm("v_permlane32_swap_b32 %0, %1" : "+v"(x2), "+v"(y2)); \
      i32x4 pp; \
      pp[0] = (int)x1; pp[1] = (int)x2; pp[2] = (int)y1; pp[3] = (int)y2; \
      pa[ks] = __builtin_bit_cast(bf16x8, pp); }
    PACK(0, s0, 0) PACK(1, s0, 8) PACK(2, s1, 0) PACK(3, s1, 8)
#undef PACK

    // ---- stage tile kt+1 into lds[nb]; issue loads for kt+2 ----
    __syncthreads();   // all waves done reading lds[nb] old content (PV(kt-1))
    if (kt < 31) {
      char* Kn = (char*)&lds[nb][0];
      char* Vn = (char*)&lds[nb][8192];
#pragma unroll
      for (int i = 0; i < 4; ++i) {
        *(f32x4*)(Kn + krow[i] * 256 + ((kcol * 16) ^ ((krow[i] & 7) << 4))) = sk[i];
        *(f32x4*)(Vn + vrow[i] * 128 + ((vc * 16) ^ ((vrow[i] & 7) << 4))) = sv[i];
      }
      if (kt < 30) {
        int kv0 = (kt + 2) * 64;
#pragma unroll
        for (int i = 0; i < 4; ++i) {
          sk[i] = *(const f32x4*)(Kp + (kv0 + krow[i]) * 128 + kcol * 8);
          sv[i] = *(const f32x4*)(Vp + vrow[i] * 2048 + kv0 + vc * 8);
        }
      }
    }
    __syncthreads();   // lds[nb] (tile kt+1) visible

    // ---- contiguous MFMA cluster: QK(kt+1) then PV(kt) ----
    __builtin_amdgcn_s_setprio(1);
    if (kt < 31) qk_step((const char*)&lds[nb][0], qf, lc, hi, s0, s1);
    const char* Vb_ = (const char*)&lds[kt & 1][8192];
#pragma unroll
    for (int ks = 0; ks < 4; ++ks) {
      int cb = ks * 32 + hi * 16;
#pragma unroll
      for (int dt = 0; dt < 4; ++dt) {
        int vr = dt * 32 + lc;
        bf16x8 vb = *(const bf16x8*)(Vb_ + vr * 128 + (cb ^ ((vr & 7) << 4)));
        acc[dt] = __builtin_amdgcn_mfma_f32_32x32x16_bf16(pa[ks], vb, acc[dt], 0, 0, 0);
      }
    }
    __builtin_amdgcn_s_setprio(0);
  }

  // epilogue: O[q=crow(r,hi)][dd=dt*32+lc] / l_run[q] -> att[b, s, h*128+dd] (bf16)
  int b = bh >> 3, h = bh & 7;
#pragma unroll
  for (int r = 0; r < 16; ++r) {
    int qr = (r & 3) + 8 * (r >> 2) + 4 * hi;
    float linv = 1.f / __shfl(l_run, qr, 32);
    unsigned short* orow = att + ((b * 2048 + (q0 + qr)) * 8 + h) * 128 + lc;
#pragma unroll
    for (int dt = 0; dt < 4; ++dt) orow[dt * 32] = f2bf(acc[dt][r] * linv);
  }
}

// 64x64 output tile from As(64x128) x Bs(64x128)^T, both swizzled
__device__ __forceinline__ void mfma_64x64(const unsigned short* As, const unsigned short* Bs,
                                           int w, int l, f32x4 acc[4]) {
  int lc = l & 15, kg = l >> 4;
#pragma unroll
  for (int kc = 0; kc < 4; ++kc) {
    int ar = w * 16 + lc;
    bf16x8 a = *(const bf16x8*)((const char*)As + ar * 256 + ((kc * 64 + kg * 16) ^ ((ar & 7) << 4)));
#pragma unroll
    for (int tt = 0; tt < 4; ++tt) {
      int br = tt * 16 + lc;
      bf16x8 b = *(const bf16x8*)((const char*)Bs + br * 256 + ((kc * 64 + kg * 16) ^ ((br & 7) << 4)));
      acc[tt] = __builtin_amdgcn_mfma_f32_16x16x32_bf16(a, b, acc[tt], 0, 0, 0);
    }
  }
}

// ---------------- output projection: out = att @ Wo + bo (fp32 out) ----------------
__global__ __launch_bounds__(256) void out_proj_kernel(const unsigned short* __restrict__ att,
    const unsigned short* __restrict__ Wot, const float* __restrict__ bo,
    float* __restrict__ out) {
  __shared__ unsigned short As[64 * 128], Bs[64 * 128];
  int m0 = blockIdx.x * 64, n0 = blockIdx.y * 64;
  int t = threadIdx.x, w = t >> 6, l = t & 63, lc = l & 15, kg = l >> 4;
  f32x4 acc[4];
#pragma unroll
  for (int i = 0; i < 4; ++i) acc[i] = (f32x4){0.f, 0.f, 0.f, 0.f};
  f32x4 ra[4], rb[4];
#pragma unroll
  for (int it = 0; it < 4; ++it) {
    int c = t + it * 256, row = c >> 4, col = c & 15;
    ra[it] = *(const f32x4*)(att + (m0 + row) * 1024 + col * 8);
    rb[it] = *(const f32x4*)(Wot + (n0 + row) * 1024 + col * 8);
  }
  for (int kt = 0; kt < 8; ++kt) {
    if (kt) __syncthreads();
#pragma unroll
    for (int it = 0; it < 4; ++it) {
      int c = t + it * 256, row = c >> 4, col = c & 15;
      *(f32x4*)((char*)As + row * 256 + ((col * 16) ^ ((row & 7) << 4))) = ra[it];
      *(f32x4*)((char*)Bs + row * 256 + ((col * 16) ^ ((row & 7) << 4))) = rb[it];
    }
    __syncthreads();
    if (kt < 7) {
#pragma unroll
      for (int it = 0; it < 4; ++it) {
        int c = t + it * 256, row = c >> 4, col = c & 15;
        ra[it] = *(const f32x4*)(att + (m0 + row) * 1024 + (kt + 1) * 128 + col * 8);
        rb[it] = *(const f32x4*)(Wot + (n0 + row) * 1024 + (kt + 1) * 128 + col * 8);
      }
    }
    mfma_64x64(As, Bs, w, l, acc);
  }
#pragma unroll
  for (int tt = 0; tt < 4; ++tt)
#pragma unroll
    for (int e = 0; e < 4; ++e) {
      int m = m0 + w * 16 + kg * 4 + e;
      int n = n0 + tt * 16 + lc;
      out[m * 128 + n] = acc[tt][e] + bo[n];
    }
}

extern "C" void kernel_launch(void* const* d_in, const int* in_sizes, int n_in,
                              void* d_out, int out_size, void* d_ws, size_t ws_size,
                              hipStream_t stream) {
  const float* x  = (const float*)d_in[0];
  const float* Wq = (const float*)d_in[1];
  const float* Wk = (const float*)d_in[2];
  const float* Wv = (const float*)d_in[3];
  const float* Wo = (const float*)d_in[4];
  const float* bo = (const float*)d_in[5];
  float* out = (float*)d_out;
  char* ws = (char*)d_ws;
  unsigned short* xb  = (unsigned short*)(ws);
  unsigned short* Wtq = (unsigned short*)(ws + (2u << 20));
  unsigned short* Wtk = (unsigned short*)(ws + (2u << 20) + (256u << 10));
  unsigned short* Wtv = (unsigned short*)(ws + (2u << 20) + (512u << 10));
  unsigned short* Wot = (unsigned short*)(ws + (2u << 20) + (768u << 10));
  unsigned short* Qb  = (unsigned short*)(ws + (3u << 20));
  unsigned short* Kb  = (unsigned short*)(ws + (3u << 20) + (16u << 20));
  unsigned short* Vt  = (unsigned short*)(ws + (3u << 20) + (32u << 20));
  unsigned short* att = (unsigned short*)(ws + (3u << 20) + (48u << 20));

  hipLaunchKernelGGL(prep_kernel, dim3(640), dim3(256), 0, stream,
                     x, Wq, Wk, Wv, Wo, xb, Wtq, Wtk, Wtv, Wot);
  hipLaunchKernelGGL(qkv_kernel, dim3(64, 8), dim3(256), 0, stream,
                     xb, Wtq, Wtk, Wtv, Qb, Kb, Vt);
  hipLaunchKernelGGL(attn_kernel, dim3(512), dim3(256), 0, stream,
                     Qb, Kb, Vt, att);
  hipLaunchKernelGGL(out_proj_kernel, dim3(128, 2), dim3(256), 0, stream,
                     att, Wot, bo, out);
}